// Round 8
// baseline (289.600 us; speedup 1.0000x reference)
//
#include <hip/hip_runtime.h>

// Problem constants (fixed by reference)
constexpr int N_  = 10000;   // nodes (< 65536 -> u16 src)
constexpr int E_  = 320000;  // edges
constexpr int F1  = 33;      // input features
constexpr int H   = 32;      // hidden
constexpr int G   = 64;      // graphs
constexpr int CAP = 96;      // padded CSR slots/node (deg~Poisson(32), P(overflow)~1e-18/node)

// 1250 blocks x 256 threads: exactly 1 edge/thread (1250*256 = E_) in build,
// 1 node-task/block (1250*8 = N_) in agg. Multi-dispatch: kernel boundaries
// provide the sync; NO in-kernel device fences (rounds 2-4: fence storms cost
// 400+ us). Device-scope ATOMICS are cheap (coherence-point ops, no L2 flush).
constexpr int GRID = 1250;
constexpr int BT   = 256;

// round-to-nearest-even f32 -> bf16 (low 16 bits)
__device__ __forceinline__ unsigned bf16r(float x) {
    unsigned u = __float_as_uint(x);
    return (u + 0x7FFFu + ((u >> 16) & 1u)) >> 16;
}

struct Prm {
    const float* x; const int* ei; const float* ea; const int* batch;
    const float* A1; const float* B1; const float* R1; const float* z1;
    const float* A2; const float* B2; const float* R2; const float* z2;
    const float* A3; const float* B3; const float* R3; const float* z3;
    const float* l1w; const float* l1b; const float* l2w; const float* l2b;
    int* counts; int* startsP; unsigned* meta;
    unsigned* UVa; float* Ra; unsigned* UVb; float* Rb;
    float* psum; unsigned* pmax;    // per-graph pooled accumulators [G][H]
    int* done;                      // agg3 completion counter
    float* out;
};

// ---- build padded CSR (node-major meta) + layer-1 UV/R + graph starts ----
__global__ __launch_bounds__(BT, 5) void k_build(Prm p) {
    const int tid = threadIdx.x, bid = blockIdx.x;
    {   // exactly one edge per thread
        int e = bid * BT + tid;
        int s = p.ei[e];
        int d = p.ei[E_ + e];
        float av = p.ea[e];
        int pos = atomicAdd(&p.counts[d], 1);
        p.meta[(size_t)d * CAP + pos] = (unsigned)s | (bf16r(av) << 16);
    }
    const int grp = tid >> 5, f = tid & 31;   // 8 node-groups x 32 features
    const int node = bid * 8 + grp;           // one task of 8 nodes per block
    if (f == 0) {                             // graph-boundary detection (batch sorted)
        int b = p.batch[node];
        int bp = (node == 0) ? -1 : p.batch[node - 1];
        if (b != bp) p.startsP[b] = node + 1;
    }
    float u = 0.f, v = 0.f, r = p.z1[f];
    const float* xr = p.x + (size_t)node * F1;
    #pragma unroll
    for (int k = 0; k < F1; ++k) {
        float xv = xr[k];
        u = fmaf(xv, p.A1[k * H + f], u);
        v = fmaf(xv, p.B1[k * H + f], v);
        r = fmaf(xv, p.R1[k * H + f], r);
    }
    p.UVa[(node << 5) | f] = bf16r(u) | (bf16r(v) << 16);  // node-major, coalesced
    p.Ra [(node << 5) | f] = r;
}

// ---- readout (inlined into agg3's last-finishing block): 8 graphs in parallel ----
__device__ __forceinline__ void readout(const Prm& p, int* sst, float (*gpl)[3 * H]) {
    const int tid = threadIdx.x;
    if (tid < G) sst[tid] = p.startsP[tid];
    __syncthreads();
    const int grp = tid >> 5, l = tid & 31;
    for (int g = grp; g < G; g += 8) {
        int sp = sst[g];
        int s0 = 0, e0 = 0;
        if (sp != 0) {
            s0 = sp - 1;
            e0 = N_;
            for (int j = g + 1; j < G; ++j)
                if (sst[j]) { e0 = sst[j] - 1; break; }
        }
        // coherence-point reads of the pooled accumulators (atomic RMW identity)
        float sum = atomicAdd(&p.psum[g * H + l], 0.f);
        float mx  = __uint_as_float(atomicMax(&p.pmax[g * H + l], 0u));
        float c = fmaxf((float)(e0 - s0), 1.0f);
        gpl[grp][l] = sum;
        gpl[grp][H + l] = sum / c;
        gpl[grp][2 * H + l] = mx;
        // same-wave LDS write->read (32-lane group): no barrier needed
        float hacc = p.l1b[l];
        #pragma unroll
        for (int k = 0; k < H; ++k) {
            hacc = fmaf(gpl[grp][k],         p.l1w[k * H + l], hacc);
            hacc = fmaf(gpl[grp][H + k],     p.l1w[(H + k) * H + l], hacc);
            hacc = fmaf(gpl[grp][2 * H + k], p.l1w[(2 * H + k) * H + l], hacc);
        }
        float hid = fmaxf(hacc, 0.f);
        float p0 = hid * p.l2w[l * 2 + 0];
        float p1 = hid * p.l2w[l * 2 + 1];
        #pragma unroll
        for (int o = 16; o; o >>= 1) {
            p0 += __shfl_xor(p0, o, 32);
            p1 += __shfl_xor(p1, o, 32);
        }
        if (l == 0) {
            float l0 = p0 + p.l2b[0], l1 = p1 + p.l2b[1];
            float m = fmaxf(l0, l1);
            float lse = m + logf(expf(l0 - m) + expf(l1 - m));
            p.out[g * 2 + 0] = l0 - lse;
            p.out[g * 2 + 1] = l1 - lse;
        }
    }
}

// ---- aggregation (+ fused next-layer precompute for LAYER 1,2; pool+readout for 3) ----
// Half-wave (32 lanes) = 1 node. uint4 gathers: one instr fetches 4 source rows.
// Flat-8 issue for slots 0..31 AND (when needed) 32..63: one latency round each.
// Per-node scalar loads + first gather issues hoisted ABOVE the wL staging
// barrier so gather latency overlaps staging.
template<int LAYER>
__global__ __launch_bounds__(BT, 5) void k_agg(Prm p) {
    __shared__ float wL[3][H * H];   // 12 KB next-layer weights (LAYER 1,2)
    __shared__ float sh[8][H];       // LAYER 3 pooling exchange
    __shared__ int   sst[G];         // LAYER 3 readout
    __shared__ float gpl[8][3 * H];
    __shared__ int   lastf;
    const int tid = threadIdx.x;

    const unsigned* UVin; const float* Rin; unsigned* UVout; float* Rout;
    if (LAYER == 1)      { UVin = p.UVa; Rin = p.Ra; UVout = p.UVb; Rout = p.Rb; }
    else if (LAYER == 2) { UVin = p.UVb; Rin = p.Rb; UVout = p.UVa; Rout = p.Ra; }
    else                 { UVin = p.UVa; Rin = p.Ra; UVout = nullptr; Rout = nullptr; }

    const int lane = tid & 63, wav = tid >> 6;
    const int l2 = lane & 31;            // index within half-wave (= feature lane)
    const int rg = l2 >> 3;              // gather row-group 0..3
    const int fq = l2 & 7;               // feature-quad 0..7
    const int n = blockIdx.x * 8 + wav * 2 + (lane >> 5);   // node of this half-wave

    // ---- per-node loads issued FIRST (overlap wL staging below) ----
    const int dg = p.counts[n];
    const unsigned* mrow = p.meta + (size_t)n * CAP;
    unsigned m0 = mrow[l2];
    float r = Rin[(n << 5) | l2];

    // ---- stage next-layer weights (LAYER 1,2) while loads are in flight ----
    if (LAYER == 1) {
        for (int i = tid; i < H * H; i += BT) {
            wL[0][i] = p.A2[i]; wL[1][i] = p.B2[i]; wL[2][i] = p.R2[i];
        }
    } else if (LAYER == 2) {
        for (int i = tid; i < H * H; i += BT) {
            wL[0][i] = p.A3[i]; wL[1][i] = p.B3[i]; wL[2][i] = p.R3[i];
        }
    }

    float a0 = 0.f, a1 = 0.f, a2 = 0.f, a3 = 0.f;
    uint4 wq[8]; unsigned mq[8];

    auto issue = [&](unsigned mreg, int t, int sl) {
        int j = 4 * t + rg;                                  // slot of this row-group
        unsigned mv = __shfl(mreg, (lane & 32) | (j & 31), 64);
        mq[sl] = mv;
        unsigned src = min(mv & 0xFFFFu, (unsigned)(N_ - 1));
        wq[sl] = *reinterpret_cast<const uint4*>(UVin + ((size_t)src << 5) + 4 * fq);
    };
    auto use = [&](int t, int sl) {
        unsigned mv = mq[sl]; uint4 w = wq[sl];
        float a = __uint_as_float(mv & 0xFFFF0000u);         // edge weight (bf16 hi)
        bool live = (4 * t + rg) < dg;
        float t0 = fmaf(a, __uint_as_float(w.x << 16), __uint_as_float(w.x & 0xFFFF0000u));
        float t1 = fmaf(a, __uint_as_float(w.y << 16), __uint_as_float(w.y & 0xFFFF0000u));
        float t2 = fmaf(a, __uint_as_float(w.z << 16), __uint_as_float(w.z & 0xFFFF0000u));
        float t3 = fmaf(a, __uint_as_float(w.w << 16), __uint_as_float(w.w & 0xFFFF0000u));
        if (live) { a0 += t0; a1 += t1; a2 += t2; a3 += t3; }
    };

    // slots 0..31: flat-8 issue (before the staging barrier - overlaps it)
    #pragma unroll
    for (int t = 0; t < 8; ++t) issue(m0, t, t);
    const bool need1 = __any(dg > 32);                       // ~71% of waves
    unsigned m1 = 0;
    if (need1) m1 = mrow[32 + l2];                           // hides under consume
    if (LAYER < 3) __syncthreads();                          // wL ready
    #pragma unroll
    for (int t = 0; t < 8; ++t) use(t, t);
    if (need1) {                                             // slots 32..63, one round
        #pragma unroll
        for (int t = 8; t < 16; ++t) issue(m1, t, t - 8);
        #pragma unroll
        for (int t = 8; t < 16; ++t) use(t, t - 8);
        if (__any(dg > 64)) {                                // ~never: slots 64..95
            unsigned m2 = mrow[64 + l2];
            #pragma unroll
            for (int t = 16; t < 24; ++t) issue(m2, t, t - 16);
            #pragma unroll
            for (int t = 16; t < 24; ++t) use(t, t - 16);
        }
    }

    // reduce over the 4 row-groups (masks 8,16 stay within the half-wave)
    a0 += __shfl_xor(a0, 8);  a0 += __shfl_xor(a0, 16);
    a1 += __shfl_xor(a1, 8);  a1 += __shfl_xor(a1, 16);
    a2 += __shfl_xor(a2, 8);  a2 += __shfl_xor(a2, 16);
    a3 += __shfl_xor(a3, 8);  a3 += __shfl_xor(a3, 16);

    // reshuffle quad-layout -> feature-per-lane
    int rsrc = (lane & 32) | (l2 >> 2);
    float s0 = __shfl(a0, rsrc, 64), s1 = __shfl(a1, rsrc, 64);
    float s2 = __shfl(a2, rsrc, 64), s3 = __shfl(a3, rsrc, 64);
    int c = l2 & 3;
    float accf = (c == 0) ? s0 : (c == 1) ? s1 : (c == 2) ? s2 : s3;

    float h = fmaxf(r + accf, 0.f);                          // h[n][f], f = l2

    if (LAYER == 3) {
        // pooling folded in: block-local reduce then device atomics
        sh[wav * 2 + (lane >> 5)][l2] = h;
        __syncthreads();
        if (tid < 32) {
            const int f = tid;
            const int n0 = blockIdx.x * 8;
            float s = 0.f, mx = 0.f;
            int cg = p.batch[n0];
            #pragma unroll
            for (int i = 0; i < 8; ++i) {
                int bg = p.batch[n0 + i];                    // uniform -> scalar load
                if (bg != cg) {                              // flush run (rare)
                    atomicAdd(&p.psum[cg * H + f], s);
                    atomicMax(&p.pmax[cg * H + f], __float_as_uint(mx));  // h >= 0
                    s = 0.f; mx = 0.f; cg = bg;
                }
                float hv = sh[i][f];
                s += hv; mx = fmaxf(mx, hv);
            }
            atomicAdd(&p.psum[cg * H + f], s);
            atomicMax(&p.pmax[cg * H + f], __float_as_uint(mx));
        }
        // done-counter: block's atomics are complete (post-barrier) before signal
        __syncthreads();
        if (tid == 0) {
            int d = __hip_atomic_fetch_add(p.done, 1, __ATOMIC_ACQ_REL,
                                           __HIP_MEMORY_SCOPE_AGENT);
            lastf = (d == GRID - 1);
        }
        __syncthreads();
        if (lastf) readout(p, sst, gpl);                     // last finisher reads out
    } else {
        // fused next-layer precompute (f = l2)
        const float zf = (LAYER == 1) ? p.z2[l2] : p.z3[l2];
        float u = 0.f, v = 0.f, rn = zf;
        #pragma unroll
        for (int k = 0; k < H; ++k) {
            float hk = __shfl(h, k, 32);
            u  = fmaf(hk, wL[0][k * H + l2], u);
            v  = fmaf(hk, wL[1][k * H + l2], v);
            rn = fmaf(hk, wL[2][k * H + l2], rn);
        }
        UVout[(n << 5) | l2] = bf16r(u) | (bf16r(v) << 16);
        Rout [(n << 5) | l2] = rn;
    }
}

// ---------------- launch: 5 dispatches, no in-kernel global sync ----------------

extern "C" void kernel_launch(void* const* d_in, const int* in_sizes, int n_in,
                              void* d_out, int out_size, void* d_ws, size_t ws_size,
                              hipStream_t stream) {
    const float* x      = (const float*)d_in[0];
    const int*   ei     = (const int*)  d_in[1];
    const float* ea     = (const float*)d_in[2];
    const int*   batch  = (const int*)  d_in[3];
    const float* nn_w1  = (const float*)d_in[4];
    const float* nn_b1  = (const float*)d_in[5];
    const float* root1  = (const float*)d_in[6];
    const float* bias1  = (const float*)d_in[7];
    const float* nn_w2  = (const float*)d_in[8];
    const float* nn_b2  = (const float*)d_in[9];
    const float* root2  = (const float*)d_in[10];
    const float* bias2  = (const float*)d_in[11];
    const float* nn_w3  = (const float*)d_in[12];
    const float* nn_b3  = (const float*)d_in[13];
    const float* root3  = (const float*)d_in[14];
    const float* bias3  = (const float*)d_in[15];
    const float* lin1_w = (const float*)d_in[16];
    const float* lin1_b = (const float*)d_in[17];
    const float* lin2_w = (const float*)d_in[18];
    const float* lin2_b = (const float*)d_in[19];
    float* out = (float*)d_out;

    char* ws = (char*)d_ws;
    size_t off = 0;
    auto alloc = [&](size_t bytes) -> void* {
        void* p = ws + off;
        off += (bytes + 255) & ~(size_t)255;
        return p;
    };
    // zero-init chunk: counts | startsP | psum | pmax | done (one ~57KB memset)
    const size_t zb0 = N_ * sizeof(int);
    const size_t zb1 = zb0 + G * sizeof(int);
    const size_t zb2 = zb1 + G * H * sizeof(float);
    const size_t zb3 = zb2 + G * H * sizeof(unsigned);
    const size_t zbytes = zb3 + sizeof(int);
    char* zchunk = (char*)alloc(zbytes);
    int*      counts  = (int*)zchunk;
    int*      startsP = (int*)(zchunk + zb0);
    float*    psum    = (float*)(zchunk + zb1);
    unsigned* pmax    = (unsigned*)(zchunk + zb2);
    int*      done    = (int*)(zchunk + zb3);
    unsigned* meta = (unsigned*)alloc((size_t)N_ * CAP * sizeof(unsigned)); // 3.84 MB
    unsigned* UVa = (unsigned*)alloc((size_t)N_ * H * sizeof(unsigned));
    float*    Ra  = (float*)   alloc((size_t)N_ * H * sizeof(float));
    unsigned* UVb = (unsigned*)alloc((size_t)N_ * H * sizeof(unsigned));
    float*    Rb  = (float*)   alloc((size_t)N_ * H * sizeof(float));

    Prm prm{ x, ei, ea, batch,
             nn_w1, nn_b1, root1, bias1,
             nn_w2, nn_b2, root2, bias2,
             nn_w3, nn_b3, root3, bias3,
             lin1_w, lin1_b, lin2_w, lin2_b,
             counts, startsP, meta, UVa, Ra, UVb, Rb, psum, pmax, done, out };

    hipMemsetAsync(zchunk, 0, zbytes, stream);
    k_build <<<GRID, BT, 0, stream>>>(prm);
    k_agg<1><<<GRID, BT, 0, stream>>>(prm);
    k_agg<2><<<GRID, BT, 0, stream>>>(prm);
    k_agg<3><<<GRID, BT, 0, stream>>>(prm);
}

// Round 9
// 284.726 us; speedup vs baseline: 1.0171x; 1.0171x over previous
//
#include <hip/hip_runtime.h>

// Problem constants (fixed by reference)
constexpr int N_  = 10000;   // nodes (< 65536 -> u16 src)
constexpr int E_  = 320000;  // edges
constexpr int F1  = 33;      // input features
constexpr int H   = 32;      // hidden
constexpr int G   = 64;      // graphs
constexpr int CAP = 96;      // padded CSR slots/node (deg~Poisson(32), P(overflow)~1e-18/node)

// 1250 blocks x 256 threads: exactly 1 edge/thread (1250*256 = E_) in build,
// 1 node-task/block (1250*8 = N_) in agg. Multi-dispatch: kernel boundaries
// provide the sync; NO ordered (acq/rel) device-scope ops anywhere:
//   - rounds 2-4: fence storms cost 400+ us
//   - round 8: ONE acq_rel atomic per block made agg3 alone 163 us.
// RELAXED device-scope atomics are cheap (coherence-point ops, no cache
// maintenance): build's 320K + agg3's 160K pooling atomics are ~1-2 us.
// Correctness of the relaxed done-counter: __syncthreads() emits
// s_waitcnt vmcnt(0) before s_barrier, so the block's pooling atomics are
// COMPLETE at the coherence point before the done-increment issues; the
// readout reads psum/pmax via atomic-RMW identity ops (also coherence-point),
// so it observes final values with no acquire fence.
constexpr int GRID = 1250;
constexpr int BT   = 256;

// round-to-nearest-even f32 -> bf16 (low 16 bits)
__device__ __forceinline__ unsigned bf16r(float x) {
    unsigned u = __float_as_uint(x);
    return (u + 0x7FFFu + ((u >> 16) & 1u)) >> 16;
}

struct Prm {
    const float* x; const int* ei; const float* ea; const int* batch;
    const float* A1; const float* B1; const float* R1; const float* z1;
    const float* A2; const float* B2; const float* R2; const float* z2;
    const float* A3; const float* B3; const float* R3; const float* z3;
    const float* l1w; const float* l1b; const float* l2w; const float* l2b;
    int* counts; int* startsP; unsigned* meta;
    unsigned* UVa; float* Ra; unsigned* UVb; float* Rb;
    float* psum; unsigned* pmax;    // per-graph pooled accumulators [G][H]
    int* done;                      // agg3 completion counter
    float* out;
};

// ---- build padded CSR (node-major meta) + layer-1 UV/R + graph starts ----
__global__ __launch_bounds__(BT, 5) void k_build(Prm p) {
    const int tid = threadIdx.x, bid = blockIdx.x;
    {   // exactly one edge per thread
        int e = bid * BT + tid;
        int s = p.ei[e];
        int d = p.ei[E_ + e];
        float av = p.ea[e];
        int pos = atomicAdd(&p.counts[d], 1);
        p.meta[(size_t)d * CAP + pos] = (unsigned)s | (bf16r(av) << 16);
    }
    const int grp = tid >> 5, f = tid & 31;   // 8 node-groups x 32 features
    const int node = bid * 8 + grp;           // one task of 8 nodes per block
    if (f == 0) {                             // graph-boundary detection (batch sorted)
        int b = p.batch[node];
        int bp = (node == 0) ? -1 : p.batch[node - 1];
        if (b != bp) p.startsP[b] = node + 1;
    }
    float u = 0.f, v = 0.f, r = p.z1[f];
    const float* xr = p.x + (size_t)node * F1;
    #pragma unroll
    for (int k = 0; k < F1; ++k) {
        float xv = xr[k];
        u = fmaf(xv, p.A1[k * H + f], u);
        v = fmaf(xv, p.B1[k * H + f], v);
        r = fmaf(xv, p.R1[k * H + f], r);
    }
    p.UVa[(node << 5) | f] = bf16r(u) | (bf16r(v) << 16);  // node-major, coalesced
    p.Ra [(node << 5) | f] = r;
}

// ---- readout (inlined into agg3's last-finishing block): 8 graphs in parallel ----
__device__ __forceinline__ void readout(const Prm& p, int* sst, float (*gpl)[3 * H]) {
    const int tid = threadIdx.x;
    if (tid < G) sst[tid] = p.startsP[tid];
    __syncthreads();
    const int grp = tid >> 5, l = tid & 31;
    for (int g = grp; g < G; g += 8) {
        int sp = sst[g];
        int s0 = 0, e0 = 0;
        if (sp != 0) {
            s0 = sp - 1;
            e0 = N_;
            for (int j = g + 1; j < G; ++j)
                if (sst[j]) { e0 = sst[j] - 1; break; }
        }
        // coherence-point reads of the pooled accumulators (atomic RMW identity)
        float sum = atomicAdd(&p.psum[g * H + l], 0.f);
        float mx  = __uint_as_float(atomicMax(&p.pmax[g * H + l], 0u));
        float c = fmaxf((float)(e0 - s0), 1.0f);
        gpl[grp][l] = sum;
        gpl[grp][H + l] = sum / c;
        gpl[grp][2 * H + l] = mx;
        // same-wave LDS write->read (32-lane group): no barrier needed
        float hacc = p.l1b[l];
        #pragma unroll
        for (int k = 0; k < H; ++k) {
            hacc = fmaf(gpl[grp][k],         p.l1w[k * H + l], hacc);
            hacc = fmaf(gpl[grp][H + k],     p.l1w[(H + k) * H + l], hacc);
            hacc = fmaf(gpl[grp][2 * H + k], p.l1w[(2 * H + k) * H + l], hacc);
        }
        float hid = fmaxf(hacc, 0.f);
        float p0 = hid * p.l2w[l * 2 + 0];
        float p1 = hid * p.l2w[l * 2 + 1];
        #pragma unroll
        for (int o = 16; o; o >>= 1) {
            p0 += __shfl_xor(p0, o, 32);
            p1 += __shfl_xor(p1, o, 32);
        }
        if (l == 0) {
            float l0 = p0 + p.l2b[0], l1 = p1 + p.l2b[1];
            float m = fmaxf(l0, l1);
            float lse = m + logf(expf(l0 - m) + expf(l1 - m));
            p.out[g * 2 + 0] = l0 - lse;
            p.out[g * 2 + 1] = l1 - lse;
        }
    }
}

// ---- aggregation (+ fused next-layer precompute for LAYER 1,2; pool+readout for 3) ----
// Half-wave (32 lanes) = 1 node. uint4 gathers: one instr fetches 4 source rows.
// Flat-8 issue for slots 0..31 AND (when needed) 32..63: one latency round each.
// Per-node scalar loads + first gather issues hoisted ABOVE the wL staging
// barrier so gather latency overlaps staging.
template<int LAYER>
__global__ __launch_bounds__(BT, 5) void k_agg(Prm p) {
    __shared__ float wL[3][H * H];   // 12 KB next-layer weights (LAYER 1,2)
    __shared__ float sh[8][H];       // LAYER 3 pooling exchange
    __shared__ int   sst[G];         // LAYER 3 readout
    __shared__ float gpl[8][3 * H];
    __shared__ int   lastf;
    const int tid = threadIdx.x;

    const unsigned* UVin; const float* Rin; unsigned* UVout; float* Rout;
    if (LAYER == 1)      { UVin = p.UVa; Rin = p.Ra; UVout = p.UVb; Rout = p.Rb; }
    else if (LAYER == 2) { UVin = p.UVb; Rin = p.Rb; UVout = p.UVa; Rout = p.Ra; }
    else                 { UVin = p.UVa; Rin = p.Ra; UVout = nullptr; Rout = nullptr; }

    const int lane = tid & 63, wav = tid >> 6;
    const int l2 = lane & 31;            // index within half-wave (= feature lane)
    const int rg = l2 >> 3;              // gather row-group 0..3
    const int fq = l2 & 7;               // feature-quad 0..7
    const int n = blockIdx.x * 8 + wav * 2 + (lane >> 5);   // node of this half-wave

    // ---- per-node loads issued FIRST (overlap wL staging below) ----
    const int dg = p.counts[n];
    const unsigned* mrow = p.meta + (size_t)n * CAP;
    unsigned m0 = mrow[l2];
    float r = Rin[(n << 5) | l2];

    // ---- stage next-layer weights (LAYER 1,2) while loads are in flight ----
    if (LAYER == 1) {
        for (int i = tid; i < H * H; i += BT) {
            wL[0][i] = p.A2[i]; wL[1][i] = p.B2[i]; wL[2][i] = p.R2[i];
        }
    } else if (LAYER == 2) {
        for (int i = tid; i < H * H; i += BT) {
            wL[0][i] = p.A3[i]; wL[1][i] = p.B3[i]; wL[2][i] = p.R3[i];
        }
    }

    float a0 = 0.f, a1 = 0.f, a2 = 0.f, a3 = 0.f;
    uint4 wq[8]; unsigned mq[8];

    auto issue = [&](unsigned mreg, int t, int sl) {
        int j = 4 * t + rg;                                  // slot of this row-group
        unsigned mv = __shfl(mreg, (lane & 32) | (j & 31), 64);
        mq[sl] = mv;
        unsigned src = min(mv & 0xFFFFu, (unsigned)(N_ - 1));
        wq[sl] = *reinterpret_cast<const uint4*>(UVin + ((size_t)src << 5) + 4 * fq);
    };
    auto use = [&](int t, int sl) {
        unsigned mv = mq[sl]; uint4 w = wq[sl];
        float a = __uint_as_float(mv & 0xFFFF0000u);         // edge weight (bf16 hi)
        bool live = (4 * t + rg) < dg;
        float t0 = fmaf(a, __uint_as_float(w.x << 16), __uint_as_float(w.x & 0xFFFF0000u));
        float t1 = fmaf(a, __uint_as_float(w.y << 16), __uint_as_float(w.y & 0xFFFF0000u));
        float t2 = fmaf(a, __uint_as_float(w.z << 16), __uint_as_float(w.z & 0xFFFF0000u));
        float t3 = fmaf(a, __uint_as_float(w.w << 16), __uint_as_float(w.w & 0xFFFF0000u));
        if (live) { a0 += t0; a1 += t1; a2 += t2; a3 += t3; }
    };

    // slots 0..31: flat-8 issue (before the staging barrier - overlaps it)
    #pragma unroll
    for (int t = 0; t < 8; ++t) issue(m0, t, t);
    const bool need1 = __any(dg > 32);                       // ~71% of waves
    unsigned m1 = 0;
    if (need1) m1 = mrow[32 + l2];                           // hides under consume
    if (LAYER < 3) __syncthreads();                          // wL ready
    #pragma unroll
    for (int t = 0; t < 8; ++t) use(t, t);
    if (need1) {                                             // slots 32..63, one round
        #pragma unroll
        for (int t = 8; t < 16; ++t) issue(m1, t, t - 8);
        #pragma unroll
        for (int t = 8; t < 16; ++t) use(t, t - 8);
        if (__any(dg > 64)) {                                // ~never: slots 64..95
            unsigned m2 = mrow[64 + l2];
            #pragma unroll
            for (int t = 16; t < 24; ++t) issue(m2, t, t - 16);
            #pragma unroll
            for (int t = 16; t < 24; ++t) use(t, t - 16);
        }
    }

    // reduce over the 4 row-groups (masks 8,16 stay within the half-wave)
    a0 += __shfl_xor(a0, 8);  a0 += __shfl_xor(a0, 16);
    a1 += __shfl_xor(a1, 8);  a1 += __shfl_xor(a1, 16);
    a2 += __shfl_xor(a2, 8);  a2 += __shfl_xor(a2, 16);
    a3 += __shfl_xor(a3, 8);  a3 += __shfl_xor(a3, 16);

    // reshuffle quad-layout -> feature-per-lane
    int rsrc = (lane & 32) | (l2 >> 2);
    float s0 = __shfl(a0, rsrc, 64), s1 = __shfl(a1, rsrc, 64);
    float s2 = __shfl(a2, rsrc, 64), s3 = __shfl(a3, rsrc, 64);
    int c = l2 & 3;
    float accf = (c == 0) ? s0 : (c == 1) ? s1 : (c == 2) ? s2 : s3;

    float h = fmaxf(r + accf, 0.f);                          // h[n][f], f = l2

    if (LAYER == 3) {
        // pooling folded in: block-local reduce then RELAXED device atomics
        sh[wav * 2 + (lane >> 5)][l2] = h;
        __syncthreads();
        if (tid < 32) {
            const int f = tid;
            const int n0 = blockIdx.x * 8;
            float s = 0.f, mx = 0.f;
            int cg = p.batch[n0];
            #pragma unroll
            for (int i = 0; i < 8; ++i) {
                int bg = p.batch[n0 + i];                    // uniform -> scalar load
                if (bg != cg) {                              // flush run (rare)
                    atomicAdd(&p.psum[cg * H + f], s);
                    atomicMax(&p.pmax[cg * H + f], __float_as_uint(mx));  // h >= 0
                    s = 0.f; mx = 0.f; cg = bg;
                }
                float hv = sh[i][f];
                s += hv; mx = fmaxf(mx, hv);
            }
            atomicAdd(&p.psum[cg * H + f], s);
            atomicMax(&p.pmax[cg * H + f], __float_as_uint(mx));
        }
        // __syncthreads drains vmcnt(0): pooling atomics are COMPLETE at the
        // coherence point before the done-increment. RELAXED (round 8's
        // ACQ_REL here cost 140us of serialized cache maintenance).
        __syncthreads();
        if (tid == 0) {
            int d = __hip_atomic_fetch_add(p.done, 1, __ATOMIC_RELAXED,
                                           __HIP_MEMORY_SCOPE_AGENT);
            lastf = (d == GRID - 1);
        }
        __syncthreads();
        if (lastf) readout(p, sst, gpl);                     // last finisher reads out
    } else {
        // fused next-layer precompute (f = l2)
        const float zf = (LAYER == 1) ? p.z2[l2] : p.z3[l2];
        float u = 0.f, v = 0.f, rn = zf;
        #pragma unroll
        for (int k = 0; k < H; ++k) {
            float hk = __shfl(h, k, 32);
            u  = fmaf(hk, wL[0][k * H + l2], u);
            v  = fmaf(hk, wL[1][k * H + l2], v);
            rn = fmaf(hk, wL[2][k * H + l2], rn);
        }
        UVout[(n << 5) | l2] = bf16r(u) | (bf16r(v) << 16);
        Rout [(n << 5) | l2] = rn;
    }
}

// ---------------- launch: 5 dispatches, no ordered device-scope ops ----------------

extern "C" void kernel_launch(void* const* d_in, const int* in_sizes, int n_in,
                              void* d_out, int out_size, void* d_ws, size_t ws_size,
                              hipStream_t stream) {
    const float* x      = (const float*)d_in[0];
    const int*   ei     = (const int*)  d_in[1];
    const float* ea     = (const float*)d_in[2];
    const int*   batch  = (const int*)  d_in[3];
    const float* nn_w1  = (const float*)d_in[4];
    const float* nn_b1  = (const float*)d_in[5];
    const float* root1  = (const float*)d_in[6];
    const float* bias1  = (const float*)d_in[7];
    const float* nn_w2  = (const float*)d_in[8];
    const float* nn_b2  = (const float*)d_in[9];
    const float* root2  = (const float*)d_in[10];
    const float* bias2  = (const float*)d_in[11];
    const float* nn_w3  = (const float*)d_in[12];
    const float* nn_b3  = (const float*)d_in[13];
    const float* root3  = (const float*)d_in[14];
    const float* bias3  = (const float*)d_in[15];
    const float* lin1_w = (const float*)d_in[16];
    const float* lin1_b = (const float*)d_in[17];
    const float* lin2_w = (const float*)d_in[18];
    const float* lin2_b = (const float*)d_in[19];
    float* out = (float*)d_out;

    char* ws = (char*)d_ws;
    size_t off = 0;
    auto alloc = [&](size_t bytes) -> void* {
        void* p = ws + off;
        off += (bytes + 255) & ~(size_t)255;
        return p;
    };
    // zero-init chunk: counts | startsP | psum | pmax | done (one ~57KB memset)
    const size_t zb0 = N_ * sizeof(int);
    const size_t zb1 = zb0 + G * sizeof(int);
    const size_t zb2 = zb1 + G * H * sizeof(float);
    const size_t zb3 = zb2 + G * H * sizeof(unsigned);
    const size_t zbytes = zb3 + sizeof(int);
    char* zchunk = (char*)alloc(zbytes);
    int*      counts  = (int*)zchunk;
    int*      startsP = (int*)(zchunk + zb0);
    float*    psum    = (float*)(zchunk + zb1);
    unsigned* pmax    = (unsigned*)(zchunk + zb2);
    int*      done    = (int*)(zchunk + zb3);
    unsigned* meta = (unsigned*)alloc((size_t)N_ * CAP * sizeof(unsigned)); // 3.84 MB
    unsigned* UVa = (unsigned*)alloc((size_t)N_ * H * sizeof(unsigned));
    float*    Ra  = (float*)   alloc((size_t)N_ * H * sizeof(float));
    unsigned* UVb = (unsigned*)alloc((size_t)N_ * H * sizeof(unsigned));
    float*    Rb  = (float*)   alloc((size_t)N_ * H * sizeof(float));

    Prm prm{ x, ei, ea, batch,
             nn_w1, nn_b1, root1, bias1,
             nn_w2, nn_b2, root2, bias2,
             nn_w3, nn_b3, root3, bias3,
             lin1_w, lin1_b, lin2_w, lin2_b,
             counts, startsP, meta, UVa, Ra, UVb, Rb, psum, pmax, done, out };

    hipMemsetAsync(zchunk, 0, zbytes, stream);
    k_build <<<GRID, BT, 0, stream>>>(prm);
    k_agg<1><<<GRID, BT, 0, stream>>>(prm);
    k_agg<2><<<GRID, BT, 0, stream>>>(prm);
    k_agg<3><<<GRID, BT, 0, stream>>>(prm);
}

// Round 10
// 156.789 us; speedup vs baseline: 1.8471x; 1.8160x over previous
//
#include <hip/hip_runtime.h>

// Problem constants (fixed by reference)
constexpr int N_  = 10000;   // nodes (< 65536 -> u16 src)
constexpr int E_  = 320000;  // edges
constexpr int F1  = 33;      // input features
constexpr int H   = 32;      // hidden
constexpr int G   = 64;      // graphs
constexpr int CAP = 96;      // padded CSR slots/node (deg~Poisson(32), P(overflow)~1e-18/node)

// 1250 blocks x 256 threads: exactly 1 edge/thread (1250*256 = E_) in build,
// 1 node-task/block (1250*8 = N_) in agg. 6 dispatches; kernel boundaries
// provide all inter-phase sync. HARD RULES learned on this chip:
//  - NO in-kernel device fences / ordered (acq_rel) device-scope ops
//    (rounds 2-4: 400+ us; round 8: one acq_rel per block = +130 us).
//  - Device-scope atomics are cheap ONLY when address-parallel; a
//    SINGLE-LINE counter serializes at ~100ns/op (round 9: 1250 ops = 125 us).
//  - L2 persists across kernel boundaries within an iteration -> normal
//    (cached) loads let meta/UV hit L2 in later aggs; do NOT use NT hints.
constexpr int GRID = 1250;
constexpr int BT   = 256;

// round-to-nearest-even f32 -> bf16 (low 16 bits)
__device__ __forceinline__ unsigned bf16r(float x) {
    unsigned u = __float_as_uint(x);
    return (u + 0x7FFFu + ((u >> 16) & 1u)) >> 16;
}

struct Prm {
    const float* x; const int* ei; const float* ea; const int* batch;
    const float* A1; const float* B1; const float* R1; const float* z1;
    const float* A2; const float* B2; const float* R2; const float* z2;
    const float* A3; const float* B3; const float* R3; const float* z3;
    const float* l1w; const float* l1b; const float* l2w; const float* l2b;
    int* counts; int* startsP; unsigned* meta;
    unsigned* UVa; float* Ra; unsigned* UVb; float* Rb;
    float* psum; unsigned* pmax;    // per-graph pooled accumulators [G][H]
    float* out;
};

// ---- build padded CSR (node-major meta) + layer-1 UV/R + graph starts ----
__global__ __launch_bounds__(BT, 5) void k_build(Prm p) {
    const int tid = threadIdx.x, bid = blockIdx.x;
    {   // exactly one edge per thread; address-parallel atomics (10000 lines)
        int e = bid * BT + tid;
        int s = p.ei[e];
        int d = p.ei[E_ + e];
        float av = p.ea[e];
        int pos = atomicAdd(&p.counts[d], 1);
        p.meta[(size_t)d * CAP + pos] = (unsigned)s | (bf16r(av) << 16);
    }
    const int grp = tid >> 5, f = tid & 31;   // 8 node-groups x 32 features
    const int node = bid * 8 + grp;           // one task of 8 nodes per block
    if (f == 0) {                             // graph-boundary detection (batch sorted)
        int b = p.batch[node];
        int bp = (node == 0) ? -1 : p.batch[node - 1];
        if (b != bp) p.startsP[b] = node + 1;
    }
    float u = 0.f, v = 0.f, r = p.z1[f];
    const float* xr = p.x + (size_t)node * F1;
    #pragma unroll
    for (int k = 0; k < F1; ++k) {
        float xv = xr[k];
        u = fmaf(xv, p.A1[k * H + f], u);
        v = fmaf(xv, p.B1[k * H + f], v);
        r = fmaf(xv, p.R1[k * H + f], r);
    }
    p.UVa[(node << 5) | f] = bf16r(u) | (bf16r(v) << 16);  // node-major, coalesced
    p.Ra [(node << 5) | f] = r;
}

// ---- aggregation (+ fused next-layer precompute for LAYER 1,2; pooling for 3) ----
// Half-wave (32 lanes) = 1 node. uint4 gathers: one instr fetches 4 source rows.
// Flat-8 issue for slots 0..31 and (when needed) 32..63: one latency round each.
// Per-node loads + first gather issues hoisted ABOVE the wL staging barrier.
template<int LAYER>
__global__ __launch_bounds__(BT, 5) void k_agg(Prm p) {
    __shared__ float wL[3][H * H];   // 12 KB next-layer weights (LAYER 1,2)
    __shared__ float sh[8][H];       // LAYER 3 pooling exchange
    const int tid = threadIdx.x;

    const unsigned* UVin; const float* Rin; unsigned* UVout; float* Rout;
    if (LAYER == 1)      { UVin = p.UVa; Rin = p.Ra; UVout = p.UVb; Rout = p.Rb; }
    else if (LAYER == 2) { UVin = p.UVb; Rin = p.Rb; UVout = p.UVa; Rout = p.Ra; }
    else                 { UVin = p.UVa; Rin = p.Ra; UVout = nullptr; Rout = nullptr; }

    const int lane = tid & 63, wav = tid >> 6;
    const int l2 = lane & 31;            // index within half-wave (= feature lane)
    const int rg = l2 >> 3;              // gather row-group 0..3
    const int fq = l2 & 7;               // feature-quad 0..7
    const int n = blockIdx.x * 8 + wav * 2 + (lane >> 5);   // node of this half-wave

    // ---- per-node loads issued FIRST (overlap wL staging below) ----
    const int dg = p.counts[n];
    const unsigned* mrow = p.meta + (size_t)n * CAP;
    unsigned m0 = mrow[l2];
    float r = Rin[(n << 5) | l2];

    // ---- stage next-layer weights (LAYER 1,2) while loads are in flight ----
    if (LAYER == 1) {
        for (int i = tid; i < H * H; i += BT) {
            wL[0][i] = p.A2[i]; wL[1][i] = p.B2[i]; wL[2][i] = p.R2[i];
        }
    } else if (LAYER == 2) {
        for (int i = tid; i < H * H; i += BT) {
            wL[0][i] = p.A3[i]; wL[1][i] = p.B3[i]; wL[2][i] = p.R3[i];
        }
    }

    float a0 = 0.f, a1 = 0.f, a2 = 0.f, a3 = 0.f;
    uint4 wq[8]; unsigned mq[8];

    auto issue = [&](unsigned mreg, int t, int sl) {
        int j = 4 * t + rg;                                  // slot of this row-group
        unsigned mv = __shfl(mreg, (lane & 32) | (j & 31), 64);
        mq[sl] = mv;
        unsigned src = min(mv & 0xFFFFu, (unsigned)(N_ - 1));
        wq[sl] = *reinterpret_cast<const uint4*>(UVin + ((size_t)src << 5) + 4 * fq);
    };
    auto use = [&](int t, int sl) {
        unsigned mv = mq[sl]; uint4 w = wq[sl];
        float a = __uint_as_float(mv & 0xFFFF0000u);         // edge weight (bf16 hi)
        bool live = (4 * t + rg) < dg;
        float t0 = fmaf(a, __uint_as_float(w.x << 16), __uint_as_float(w.x & 0xFFFF0000u));
        float t1 = fmaf(a, __uint_as_float(w.y << 16), __uint_as_float(w.y & 0xFFFF0000u));
        float t2 = fmaf(a, __uint_as_float(w.z << 16), __uint_as_float(w.z & 0xFFFF0000u));
        float t3 = fmaf(a, __uint_as_float(w.w << 16), __uint_as_float(w.w & 0xFFFF0000u));
        if (live) { a0 += t0; a1 += t1; a2 += t2; a3 += t3; }
    };

    // slots 0..31: flat-8 issue (before the staging barrier - overlaps it)
    #pragma unroll
    for (int t = 0; t < 8; ++t) issue(m0, t, t);
    const bool need1 = __any(dg > 32);                       // ~71% of waves
    unsigned m1 = 0;
    if (need1) m1 = mrow[32 + l2];                           // hides under consume
    if (LAYER < 3) __syncthreads();                          // wL ready
    #pragma unroll
    for (int t = 0; t < 8; ++t) use(t, t);
    if (need1) {                                             // slots 32..63, one round
        #pragma unroll
        for (int t = 8; t < 16; ++t) issue(m1, t, t - 8);
        #pragma unroll
        for (int t = 8; t < 16; ++t) use(t, t - 8);
        if (__any(dg > 64)) {                                // ~never: slots 64..95
            unsigned m2 = mrow[64 + l2];
            #pragma unroll
            for (int t = 16; t < 24; ++t) issue(m2, t, t - 16);
            #pragma unroll
            for (int t = 16; t < 24; ++t) use(t, t - 16);
        }
    }

    // reduce over the 4 row-groups (masks 8,16 stay within the half-wave)
    a0 += __shfl_xor(a0, 8);  a0 += __shfl_xor(a0, 16);
    a1 += __shfl_xor(a1, 8);  a1 += __shfl_xor(a1, 16);
    a2 += __shfl_xor(a2, 8);  a2 += __shfl_xor(a2, 16);
    a3 += __shfl_xor(a3, 8);  a3 += __shfl_xor(a3, 16);

    // reshuffle quad-layout -> feature-per-lane
    int rsrc = (lane & 32) | (l2 >> 2);
    float s0 = __shfl(a0, rsrc, 64), s1 = __shfl(a1, rsrc, 64);
    float s2 = __shfl(a2, rsrc, 64), s3 = __shfl(a3, rsrc, 64);
    int c = l2 & 3;
    float accf = (c == 0) ? s0 : (c == 1) ? s1 : (c == 2) ? s2 : s3;

    float h = fmaxf(r + accf, 0.f);                          // h[n][f], f = l2

    if (LAYER == 3) {
        // pooling folded in: block-local reduce then address-parallel atomics
        sh[wav * 2 + (lane >> 5)][l2] = h;
        __syncthreads();
        if (tid < 32) {
            const int f = tid;
            const int n0 = blockIdx.x * 8;
            float s = 0.f, mx = 0.f;
            int cg = p.batch[n0];
            #pragma unroll
            for (int i = 0; i < 8; ++i) {
                int bg = p.batch[n0 + i];                    // uniform -> scalar load
                if (bg != cg) {                              // flush run (rare)
                    atomicAdd(&p.psum[cg * H + f], s);
                    atomicMax(&p.pmax[cg * H + f], __float_as_uint(mx));  // h >= 0
                    s = 0.f; mx = 0.f; cg = bg;
                }
                float hv = sh[i][f];
                s += hv; mx = fmaxf(mx, hv);
            }
            atomicAdd(&p.psum[cg * H + f], s);
            atomicMax(&p.pmax[cg * H + f], __float_as_uint(mx));
        }
    } else {
        // fused next-layer precompute (f = l2)
        const float zf = (LAYER == 1) ? p.z2[l2] : p.z3[l2];
        float u = 0.f, v = 0.f, rn = zf;
        #pragma unroll
        for (int k = 0; k < H; ++k) {
            float hk = __shfl(h, k, 32);
            u  = fmaf(hk, wL[0][k * H + l2], u);
            v  = fmaf(hk, wL[1][k * H + l2], v);
            rn = fmaf(hk, wL[2][k * H + l2], rn);
        }
        UVout[(n << 5) | l2] = bf16r(u) | (bf16r(v) << 16);
        Rout [(n << 5) | l2] = rn;
    }
}

// ---- readout: 64 blocks x 64 threads, reads 16KB of pooled accumulators ----
__global__ __launch_bounds__(64, 8) void k_read(Prm p) {
    __shared__ int   sst[G];
    __shared__ float gpl[3 * H];
    const int tid = threadIdx.x;
    const int g = blockIdx.x;
    sst[tid] = p.startsP[tid];        // BT=64=G, one load each
    __syncthreads();
    int sp = sst[g];
    int s0 = 0, e0 = 0;
    if (sp != 0) {
        s0 = sp - 1;
        e0 = N_;
        for (int j = g + 1; j < G; ++j)
            if (sst[j]) { e0 = sst[j] - 1; break; }
    }
    if (tid < 32) {
        float sum = p.psum[g * H + tid];
        float mx  = __uint_as_float(p.pmax[g * H + tid]);
        float c = fmaxf((float)(e0 - s0), 1.0f);
        gpl[tid] = sum;
        gpl[H + tid] = sum / c;
        gpl[2 * H + tid] = mx;
    }
    __syncthreads();
    if (tid < 32) {
        float hacc = p.l1b[tid];
        #pragma unroll
        for (int k = 0; k < H; ++k) {
            hacc = fmaf(gpl[k],         p.l1w[k * H + tid], hacc);
            hacc = fmaf(gpl[H + k],     p.l1w[(H + k) * H + tid], hacc);
            hacc = fmaf(gpl[2 * H + k], p.l1w[(2 * H + k) * H + tid], hacc);
        }
        float hid = fmaxf(hacc, 0.f);
        float p0 = hid * p.l2w[tid * 2 + 0];
        float p1 = hid * p.l2w[tid * 2 + 1];
        #pragma unroll
        for (int o = 16; o; o >>= 1) {
            p0 += __shfl_xor(p0, o, 32);
            p1 += __shfl_xor(p1, o, 32);
        }
        if (tid == 0) {
            float l0 = p0 + p.l2b[0], l1 = p1 + p.l2b[1];
            float m = fmaxf(l0, l1);
            float lse = m + logf(expf(l0 - m) + expf(l1 - m));
            p.out[g * 2 + 0] = l0 - lse;
            p.out[g * 2 + 1] = l1 - lse;
        }
    }
}

// ---------------- launch: 6 dispatches, no ordered device-scope ops ----------------

extern "C" void kernel_launch(void* const* d_in, const int* in_sizes, int n_in,
                              void* d_out, int out_size, void* d_ws, size_t ws_size,
                              hipStream_t stream) {
    const float* x      = (const float*)d_in[0];
    const int*   ei     = (const int*)  d_in[1];
    const float* ea     = (const float*)d_in[2];
    const int*   batch  = (const int*)  d_in[3];
    const float* nn_w1  = (const float*)d_in[4];
    const float* nn_b1  = (const float*)d_in[5];
    const float* root1  = (const float*)d_in[6];
    const float* bias1  = (const float*)d_in[7];
    const float* nn_w2  = (const float*)d_in[8];
    const float* nn_b2  = (const float*)d_in[9];
    const float* root2  = (const float*)d_in[10];
    const float* bias2  = (const float*)d_in[11];
    const float* nn_w3  = (const float*)d_in[12];
    const float* nn_b3  = (const float*)d_in[13];
    const float* root3  = (const float*)d_in[14];
    const float* bias3  = (const float*)d_in[15];
    const float* lin1_w = (const float*)d_in[16];
    const float* lin1_b = (const float*)d_in[17];
    const float* lin2_w = (const float*)d_in[18];
    const float* lin2_b = (const float*)d_in[19];
    float* out = (float*)d_out;

    char* ws = (char*)d_ws;
    size_t off = 0;
    auto alloc = [&](size_t bytes) -> void* {
        void* p = ws + off;
        off += (bytes + 255) & ~(size_t)255;
        return p;
    };
    // zero-init chunk: counts | startsP | psum | pmax (one ~57KB memset)
    const size_t zb0 = N_ * sizeof(int);
    const size_t zb1 = zb0 + G * sizeof(int);
    const size_t zb2 = zb1 + G * H * sizeof(float);
    const size_t zbytes = zb2 + G * H * sizeof(unsigned);
    char* zchunk = (char*)alloc(zbytes);
    int*      counts  = (int*)zchunk;
    int*      startsP = (int*)(zchunk + zb0);
    float*    psum    = (float*)(zchunk + zb1);
    unsigned* pmax    = (unsigned*)(zchunk + zb2);
    unsigned* meta = (unsigned*)alloc((size_t)N_ * CAP * sizeof(unsigned)); // 3.84 MB
    unsigned* UVa = (unsigned*)alloc((size_t)N_ * H * sizeof(unsigned));
    float*    Ra  = (float*)   alloc((size_t)N_ * H * sizeof(float));
    unsigned* UVb = (unsigned*)alloc((size_t)N_ * H * sizeof(unsigned));
    float*    Rb  = (float*)   alloc((size_t)N_ * H * sizeof(float));

    Prm prm{ x, ei, ea, batch,
             nn_w1, nn_b1, root1, bias1,
             nn_w2, nn_b2, root2, bias2,
             nn_w3, nn_b3, root3, bias3,
             lin1_w, lin1_b, lin2_w, lin2_b,
             counts, startsP, meta, UVa, Ra, UVb, Rb, psum, pmax, out };

    hipMemsetAsync(zchunk, 0, zbytes, stream);
    k_build <<<GRID, BT, 0, stream>>>(prm);
    k_agg<1><<<GRID, BT, 0, stream>>>(prm);
    k_agg<2><<<GRID, BT, 0, stream>>>(prm);
    k_agg<3><<<GRID, BT, 0, stream>>>(prm);
    k_read  <<<G,    64, 0, stream>>>(prm);
}

// Round 11
// 153.916 us; speedup vs baseline: 1.8815x; 1.0187x over previous
//
#include <hip/hip_runtime.h>

// Problem constants (fixed by reference)
constexpr int N_  = 10000;   // nodes (< 65536 -> u16 src)
constexpr int E_  = 320000;  // edges
constexpr int F1  = 33;      // input features
constexpr int H   = 32;      // hidden
constexpr int G   = 64;      // graphs
constexpr int CAP = 96;      // padded CSR slots/node (deg~Poisson(32), P(overflow)~1e-18/node)

// 1250 blocks x 256 threads: exactly 1 edge/thread (1250*256 = E_) in build,
// 1 node-task/block (1250*8 = N_) in agg. 6 dispatches; kernel boundaries
// provide all inter-phase sync. HARD RULES learned on this chip:
//  - NO in-kernel device fences / ordered (acq_rel) device-scope ops
//    (rounds 2-4: 400+ us; round 8: one acq_rel per block = +130 us).
//  - Device-scope atomics are cheap ONLY when address-parallel; a
//    SINGLE-LINE counter serializes at ~100ns/op (round 9: 1250 ops = 125 us).
//  - Kernel-boundary acquire invalidates per-XCD L2 -> agg gathers are served
//    from L3. Aggs are L3-bandwidth/latency bound: do NOT fetch dead slots
//    (round 10 vs 7 A/B: unconditional 32..63 cost +1.6 us).
constexpr int GRID = 1250;
constexpr int BT   = 256;

// round-to-nearest-even f32 -> bf16 (low 16 bits)
__device__ __forceinline__ unsigned bf16r(float x) {
    unsigned u = __float_as_uint(x);
    return (u + 0x7FFFu + ((u >> 16) & 1u)) >> 16;
}

struct Prm {
    const float* x; const int* ei; const float* ea; const int* batch;
    const float* A1; const float* B1; const float* R1; const float* z1;
    const float* A2; const float* B2; const float* R2; const float* z2;
    const float* A3; const float* B3; const float* R3; const float* z3;
    const float* l1w; const float* l1b; const float* l2w; const float* l2b;
    int* counts; int* startsP; unsigned* meta;
    unsigned* UVa; float* Ra; unsigned* UVb; float* Rb;
    float* psum; unsigned* pmax;    // per-graph pooled accumulators [G][H]
    float* out;
};

// ---- build padded CSR (node-major meta) + layer-1 UV/R + graph starts ----
__global__ __launch_bounds__(BT, 5) void k_build(Prm p) {
    const int tid = threadIdx.x, bid = blockIdx.x;
    {   // exactly one edge per thread; address-parallel atomics (10000 lines)
        int e = bid * BT + tid;
        int s = p.ei[e];
        int d = p.ei[E_ + e];
        float av = p.ea[e];
        int pos = atomicAdd(&p.counts[d], 1);
        p.meta[(size_t)d * CAP + pos] = (unsigned)s | (bf16r(av) << 16);
    }
    const int grp = tid >> 5, f = tid & 31;   // 8 node-groups x 32 features
    const int node = bid * 8 + grp;           // one task of 8 nodes per block
    if (f == 0) {                             // graph-boundary detection (batch sorted)
        int b = p.batch[node];
        int bp = (node == 0) ? -1 : p.batch[node - 1];
        if (b != bp) p.startsP[b] = node + 1;
    }
    float u = 0.f, v = 0.f, r = p.z1[f];
    const float* xr = p.x + (size_t)node * F1;
    #pragma unroll
    for (int k = 0; k < F1; ++k) {
        float xv = xr[k];
        u = fmaf(xv, p.A1[k * H + f], u);
        v = fmaf(xv, p.B1[k * H + f], v);
        r = fmaf(xv, p.R1[k * H + f], r);
    }
    p.UVa[(node << 5) | f] = bf16r(u) | (bf16r(v) << 16);  // node-major, coalesced
    p.Ra [(node << 5) | f] = r;
}

// ---- aggregation (+ fused next-layer precompute for LAYER 1,2; pooling for 3) ----
// Half-wave (32 lanes) = 1 node. uint4 gathers: one instr fetches 4 source rows.
// Flat-8 issue for slots 0..31 (one latency round); conditional ladder for the
// tail: 32..47 on __any(dg>32) [71% of waves], 48..63 on __any(dg>48) [~2%],
// 64..95 on dg>64 [~never] -> no dead L3 fetches.
// Per-node loads + first gather issues hoisted ABOVE the wL staging barrier.
template<int LAYER>
__global__ __launch_bounds__(BT, 5) void k_agg(Prm p) {
    __shared__ float wL[3][H * H];   // 12 KB next-layer weights (LAYER 1,2)
    __shared__ float sh[8][H];       // LAYER 3 pooling exchange
    const int tid = threadIdx.x;

    const unsigned* UVin; const float* Rin; unsigned* UVout; float* Rout;
    if (LAYER == 1)      { UVin = p.UVa; Rin = p.Ra; UVout = p.UVb; Rout = p.Rb; }
    else if (LAYER == 2) { UVin = p.UVb; Rin = p.Rb; UVout = p.UVa; Rout = p.Ra; }
    else                 { UVin = p.UVa; Rin = p.Ra; UVout = nullptr; Rout = nullptr; }

    const int lane = tid & 63, wav = tid >> 6;
    const int l2 = lane & 31;            // index within half-wave (= feature lane)
    const int rg = l2 >> 3;              // gather row-group 0..3
    const int fq = l2 & 7;               // feature-quad 0..7
    const int n = blockIdx.x * 8 + wav * 2 + (lane >> 5);   // node of this half-wave

    // ---- per-node loads issued FIRST (overlap wL staging below) ----
    const int dg = p.counts[n];
    const unsigned* mrow = p.meta + (size_t)n * CAP;
    unsigned m0 = mrow[l2];
    float r = Rin[(n << 5) | l2];

    // ---- stage next-layer weights (LAYER 1,2) while loads are in flight ----
    if (LAYER == 1) {
        for (int i = tid; i < H * H; i += BT) {
            wL[0][i] = p.A2[i]; wL[1][i] = p.B2[i]; wL[2][i] = p.R2[i];
        }
    } else if (LAYER == 2) {
        for (int i = tid; i < H * H; i += BT) {
            wL[0][i] = p.A3[i]; wL[1][i] = p.B3[i]; wL[2][i] = p.R3[i];
        }
    }

    float a0 = 0.f, a1 = 0.f, a2 = 0.f, a3 = 0.f;
    uint4 wq[8]; unsigned mq[8];

    auto issue = [&](unsigned mreg, int t, int sl) {
        int j = 4 * t + rg;                                  // slot of this row-group
        unsigned mv = __shfl(mreg, (lane & 32) | (j & 31), 64);
        mq[sl] = mv;
        unsigned src = min(mv & 0xFFFFu, (unsigned)(N_ - 1));
        wq[sl] = *reinterpret_cast<const uint4*>(UVin + ((size_t)src << 5) + 4 * fq);
    };
    auto use = [&](int t, int sl) {
        unsigned mv = mq[sl]; uint4 w = wq[sl];
        float a = __uint_as_float(mv & 0xFFFF0000u);         // edge weight (bf16 hi)
        bool live = (4 * t + rg) < dg;
        float t0 = fmaf(a, __uint_as_float(w.x << 16), __uint_as_float(w.x & 0xFFFF0000u));
        float t1 = fmaf(a, __uint_as_float(w.y << 16), __uint_as_float(w.y & 0xFFFF0000u));
        float t2 = fmaf(a, __uint_as_float(w.z << 16), __uint_as_float(w.z & 0xFFFF0000u));
        float t3 = fmaf(a, __uint_as_float(w.w << 16), __uint_as_float(w.w & 0xFFFF0000u));
        if (live) { a0 += t0; a1 += t1; a2 += t2; a3 += t3; }
    };

    // slots 0..31: flat-8 issue (before the staging barrier - overlaps it)
    #pragma unroll
    for (int t = 0; t < 8; ++t) issue(m0, t, t);
    const bool need1 = __any(dg > 32);                       // ~71% of waves
    unsigned m1 = 0;
    if (need1) m1 = mrow[32 + l2];                           // hides under consume
    if (LAYER < 3) __syncthreads();                          // wL ready
    #pragma unroll
    for (int t = 0; t < 8; ++t) use(t, t);
    if (need1) {                                             // slots 32..47
        #pragma unroll
        for (int t = 8; t < 12; ++t) issue(m1, t, t - 8);
        #pragma unroll
        for (int t = 8; t < 12; ++t) use(t, t - 8);
        if (__any(dg > 48)) {                                // rare: slots 48..63
            #pragma unroll
            for (int t = 12; t < 16; ++t) issue(m1, t, t - 12);
            #pragma unroll
            for (int t = 12; t < 16; ++t) use(t, t - 12);
            if (__any(dg > 64)) {                            // ~never: slots 64..95
                unsigned m2 = mrow[64 + l2];
                #pragma unroll
                for (int t = 16; t < 24; ++t) issue(m2, t, t - 16);
                #pragma unroll
                for (int t = 16; t < 24; ++t) use(t, t - 16);
            }
        }
    }

    // reduce over the 4 row-groups (masks 8,16 stay within the half-wave)
    a0 += __shfl_xor(a0, 8);  a0 += __shfl_xor(a0, 16);
    a1 += __shfl_xor(a1, 8);  a1 += __shfl_xor(a1, 16);
    a2 += __shfl_xor(a2, 8);  a2 += __shfl_xor(a2, 16);
    a3 += __shfl_xor(a3, 8);  a3 += __shfl_xor(a3, 16);

    // reshuffle quad-layout -> feature-per-lane
    int rsrc = (lane & 32) | (l2 >> 2);
    float s0 = __shfl(a0, rsrc, 64), s1 = __shfl(a1, rsrc, 64);
    float s2 = __shfl(a2, rsrc, 64), s3 = __shfl(a3, rsrc, 64);
    int c = l2 & 3;
    float accf = (c == 0) ? s0 : (c == 1) ? s1 : (c == 2) ? s2 : s3;

    float h = fmaxf(r + accf, 0.f);                          // h[n][f], f = l2

    if (LAYER == 3) {
        // pooling folded in: block-local reduce then address-parallel atomics
        sh[wav * 2 + (lane >> 5)][l2] = h;
        __syncthreads();
        if (tid < 32) {
            const int f = tid;
            const int n0 = blockIdx.x * 8;
            float s = 0.f, mx = 0.f;
            int cg = p.batch[n0];
            #pragma unroll
            for (int i = 0; i < 8; ++i) {
                int bg = p.batch[n0 + i];                    // uniform -> scalar load
                if (bg != cg) {                              // flush run (rare)
                    atomicAdd(&p.psum[cg * H + f], s);
                    atomicMax(&p.pmax[cg * H + f], __float_as_uint(mx));  // h >= 0
                    s = 0.f; mx = 0.f; cg = bg;
                }
                float hv = sh[i][f];
                s += hv; mx = fmaxf(mx, hv);
            }
            atomicAdd(&p.psum[cg * H + f], s);
            atomicMax(&p.pmax[cg * H + f], __float_as_uint(mx));
        }
    } else {
        // fused next-layer precompute (f = l2)
        const float zf = (LAYER == 1) ? p.z2[l2] : p.z3[l2];
        float u = 0.f, v = 0.f, rn = zf;
        #pragma unroll
        for (int k = 0; k < H; ++k) {
            float hk = __shfl(h, k, 32);
            u  = fmaf(hk, wL[0][k * H + l2], u);
            v  = fmaf(hk, wL[1][k * H + l2], v);
            rn = fmaf(hk, wL[2][k * H + l2], rn);
        }
        UVout[(n << 5) | l2] = bf16r(u) | (bf16r(v) << 16);
        Rout [(n << 5) | l2] = rn;
    }
}

// ---- readout: 64 blocks x 64 threads, reads 16KB of pooled accumulators ----
__global__ __launch_bounds__(64, 8) void k_read(Prm p) {
    __shared__ int   sst[G];
    __shared__ float gpl[3 * H];
    const int tid = threadIdx.x;
    const int g = blockIdx.x;
    sst[tid] = p.startsP[tid];        // BT=64=G, one load each
    __syncthreads();
    int sp = sst[g];
    int s0 = 0, e0 = 0;
    if (sp != 0) {
        s0 = sp - 1;
        e0 = N_;
        for (int j = g + 1; j < G; ++j)
            if (sst[j]) { e0 = sst[j] - 1; break; }
    }
    if (tid < 32) {
        float sum = p.psum[g * H + tid];
        float mx  = __uint_as_float(p.pmax[g * H + tid]);
        float c = fmaxf((float)(e0 - s0), 1.0f);
        gpl[tid] = sum;
        gpl[H + tid] = sum / c;
        gpl[2 * H + tid] = mx;
    }
    __syncthreads();
    if (tid < 32) {
        float hacc = p.l1b[tid];
        #pragma unroll
        for (int k = 0; k < H; ++k) {
            hacc = fmaf(gpl[k],         p.l1w[k * H + tid], hacc);
            hacc = fmaf(gpl[H + k],     p.l1w[(H + k) * H + tid], hacc);
            hacc = fmaf(gpl[2 * H + k], p.l1w[(2 * H + k) * H + tid], hacc);
        }
        float hid = fmaxf(hacc, 0.f);
        float p0 = hid * p.l2w[tid * 2 + 0];
        float p1 = hid * p.l2w[tid * 2 + 1];
        #pragma unroll
        for (int o = 16; o; o >>= 1) {
            p0 += __shfl_xor(p0, o, 32);
            p1 += __shfl_xor(p1, o, 32);
        }
        if (tid == 0) {
            float l0 = p0 + p.l2b[0], l1 = p1 + p.l2b[1];
            float m = fmaxf(l0, l1);
            float lse = m + logf(expf(l0 - m) + expf(l1 - m));
            p.out[g * 2 + 0] = l0 - lse;
            p.out[g * 2 + 1] = l1 - lse;
        }
    }
}

// ---------------- launch: 6 dispatches, no ordered device-scope ops ----------------

extern "C" void kernel_launch(void* const* d_in, const int* in_sizes, int n_in,
                              void* d_out, int out_size, void* d_ws, size_t ws_size,
                              hipStream_t stream) {
    const float* x      = (const float*)d_in[0];
    const int*   ei     = (const int*)  d_in[1];
    const float* ea     = (const float*)d_in[2];
    const int*   batch  = (const int*)  d_in[3];
    const float* nn_w1  = (const float*)d_in[4];
    const float* nn_b1  = (const float*)d_in[5];
    const float* root1  = (const float*)d_in[6];
    const float* bias1  = (const float*)d_in[7];
    const float* nn_w2  = (const float*)d_in[8];
    const float* nn_b2  = (const float*)d_in[9];
    const float* root2  = (const float*)d_in[10];
    const float* bias2  = (const float*)d_in[11];
    const float* nn_w3  = (const float*)d_in[12];
    const float* nn_b3  = (const float*)d_in[13];
    const float* root3  = (const float*)d_in[14];
    const float* bias3  = (const float*)d_in[15];
    const float* lin1_w = (const float*)d_in[16];
    const float* lin1_b = (const float*)d_in[17];
    const float* lin2_w = (const float*)d_in[18];
    const float* lin2_b = (const float*)d_in[19];
    float* out = (float*)d_out;

    char* ws = (char*)d_ws;
    size_t off = 0;
    auto alloc = [&](size_t bytes) -> void* {
        void* p = ws + off;
        off += (bytes + 255) & ~(size_t)255;
        return p;
    };
    // zero-init chunk: counts | startsP | psum | pmax (one ~57KB memset)
    const size_t zb0 = N_ * sizeof(int);
    const size_t zb1 = zb0 + G * sizeof(int);
    const size_t zb2 = zb1 + G * H * sizeof(float);
    const size_t zbytes = zb2 + G * H * sizeof(unsigned);
    char* zchunk = (char*)alloc(zbytes);
    int*      counts  = (int*)zchunk;
    int*      startsP = (int*)(zchunk + zb0);
    float*    psum    = (float*)(zchunk + zb1);
    unsigned* pmax    = (unsigned*)(zchunk + zb2);
    unsigned* meta = (unsigned*)alloc((size_t)N_ * CAP * sizeof(unsigned)); // 3.84 MB
    unsigned* UVa = (unsigned*)alloc((size_t)N_ * H * sizeof(unsigned));
    float*    Ra  = (float*)   alloc((size_t)N_ * H * sizeof(float));
    unsigned* UVb = (unsigned*)alloc((size_t)N_ * H * sizeof(unsigned));
    float*    Rb  = (float*)   alloc((size_t)N_ * H * sizeof(float));

    Prm prm{ x, ei, ea, batch,
             nn_w1, nn_b1, root1, bias1,
             nn_w2, nn_b2, root2, bias2,
             nn_w3, nn_b3, root3, bias3,
             lin1_w, lin1_b, lin2_w, lin2_b,
             counts, startsP, meta, UVa, Ra, UVb, Rb, psum, pmax, out };

    hipMemsetAsync(zchunk, 0, zbytes, stream);
    k_build <<<GRID, BT, 0, stream>>>(prm);
    k_agg<1><<<GRID, BT, 0, stream>>>(prm);
    k_agg<2><<<GRID, BT, 0, stream>>>(prm);
    k_agg<3><<<GRID, BT, 0, stream>>>(prm);
    k_read  <<<G,    64, 0, stream>>>(prm);
}